// Round 9
// baseline (519.579 us; speedup 1.0000x reference)
//
#include <hip/hip_runtime.h>
#include <hip/hip_bf16.h>

// MoE SwiGLU FFN, top-2 of 8 experts. B=2,T=2048 -> N=4096 tokens, D=1024, F=4096.
//
//   router+tcvt13 : fused dispatch. bid<1024: router (4 tok/block, fp32 logits,
//                   top-2, softmax, x->bf16). bid>=1024: W1/W3 [E][D][F]->[E][F][D].
//   scan/build    : per-expert 128-row padded compaction; tok2row map
//   gemm1f+tcvtW2 : fused dispatch, grid y=328: y%4==0 && y/4<72 -> gemm1 tiles
//                   (proven 2-barrier 128x128 loop); other 256 rows -> W2 convert
//                   [E][F][D]->[E][D][F] overlapped under gemm1 compute.
//   gemm2f        : y = h @ W2[e]  DUAL-B: 128x256 output per block (two 128-col
//                   W2T tiles share one A tile) -> 64 MFMA / 12 glds / 24 reads
//                   per wave per K-step == gemm1's proven ratio (old single-B had
//                   32 MFMA per barrier-pair). Single-buffer BK=64, 2-barrier,
//                   split-K=2, grid 576 (~528 real = 1 full batch + remnant).
//   combine       : out[tok] = w0*(y[r0]+y2[r0]) + w1*(y[r1]+y2[r1])
//
// NOTE (rounds 1/2/4/5): deep-pipeline gemm1 variants (BK=32 dbuf, counted-vmcnt
// 2-phase, 256-row 4-phase either prefetch placement) all REGRESSED
// (237/318/224/270 us vs 185). Do not retry without changing read:MFMA ratio.

typedef float f32x4 __attribute__((ext_vector_type(4)));
typedef __bf16 bf16x8 __attribute__((ext_vector_type(8)));

constexpr int N_TOK = 4096;
constexpr int DIM   = 1024;
constexpr int FF    = 4096;
constexpr int NE    = 8;
constexpr int TOPK  = 2;
constexpr int TILE_R = 128;
constexpr int MAXROWS = 9216;             // 8192 + 8*128 padding capacity
constexpr int MAXT    = MAXROWS / TILE_R; // 72

constexpr int BK  = 64;
constexpr int BN1 = 128;                  // gemm1 F-tile
constexpr int KSPL = 2;                   // gemm2 split-K

constexpr int TCVT2_ROWS = 256;           // W2 tcvt units / 32 x-blocks
constexpr int G1_YDIM = MAXT * 4 + (TCVT2_ROWS - MAXT * 3);   // 288 + 40 = 328

// ---- workspace offsets ----
constexpr size_t OFF_TOPI   = 0;          // top_i; rewritten by build -> tok2row
constexpr size_t OFF_TOPW   = 32768;
constexpr size_t OFF_CNT    = 65536;      // counts[8] @ +0, cursor[8] @ +128
constexpr size_t OFF_SEG    = 66048;
constexpr size_t OFF_PTOK   = 67072;
constexpr size_t OFF_XBF    = 140800;
constexpr size_t OFF_H      = OFF_XBF + (size_t)N_TOK * DIM * 2;
constexpr size_t OFF_W1T    = OFF_H   + (size_t)MAXROWS * FF * 2;
constexpr size_t OFF_W3T    = OFF_W1T + (size_t)NE * DIM * FF * 2;
constexpr size_t OFF_W2T    = OFF_W3T + (size_t)NE * DIM * FF * 2;
constexpr size_t OFF_Y      = OFF_W1T;    // y  [MAXROWS][DIM] f32 overlays W1T (dead after gemm1)
constexpr size_t OFF_Y2     = OFF_W3T;    // y2 [MAXROWS][DIM] f32 overlays W3T (dead after gemm1)

static __device__ __forceinline__ unsigned short f2bf(float f) {
    unsigned int x = __float_as_uint(f);
    x += 0x7FFFu + ((x >> 16) & 1u);    // round-to-nearest-even
    return (unsigned short)(x >> 16);
}

// async global->LDS, 16B per lane. LDS dest = wave-uniform base + lane*16 (linear);
// global src is per-lane (pre-swizzled for the XOR involution).
#define GLDS16(gsrc, ldst) \
    __builtin_amdgcn_global_load_lds( \
        (const __attribute__((address_space(1))) void*)(gsrc), \
        (__attribute__((address_space(3))) void*)(ldst), 16, 0, 0)

// shared 64x64 transpose-convert tile body (fp32 [R][C] tile -> bf16 [C][R])
static __device__ __forceinline__ void tcvt_tile(
    const float* __restrict__ s, unsigned short* __restrict__ d,
    int R, int C, int rt, int ct, unsigned short (*L)[65], int t)
{
    int r = t >> 4, c4 = (t & 15) * 4;
#pragma unroll
    for (int i = 0; i < 4; ++i) {
        float4 v = *(const float4*)(s + (size_t)(rt + r + i * 16) * C + ct + c4);
        L[r + i * 16][c4 + 0] = f2bf(v.x);
        L[r + i * 16][c4 + 1] = f2bf(v.y);
        L[r + i * 16][c4 + 2] = f2bf(v.z);
        L[r + i * 16][c4 + 3] = f2bf(v.w);
    }
    __syncthreads();
#pragma unroll
    for (int it = 0; it < 2; ++it) {
        int item = t + it * 256;
        int c  = item >> 3;
        int r8 = (item & 7) * 8;
        unsigned int w0 = (unsigned int)L[r8 + 0][c] | ((unsigned int)L[r8 + 1][c] << 16);
        unsigned int w1 = (unsigned int)L[r8 + 2][c] | ((unsigned int)L[r8 + 3][c] << 16);
        unsigned int w2 = (unsigned int)L[r8 + 4][c] | ((unsigned int)L[r8 + 5][c] << 16);
        unsigned int w3 = (unsigned int)L[r8 + 6][c] | ((unsigned int)L[r8 + 7][c] << 16);
        *(uint4*)(d + (size_t)(ct + c) * R + rt + r8) = make_uint4(w0, w1, w2, w3);
    }
}

// ---------------- fused: router (bid<1024) + W1/W3 transpose-convert ----------------
__global__ __launch_bounds__(256) void router_tcvt13_kernel(
    const float* __restrict__ x, const float* __restrict__ Wg,
    int* __restrict__ top_i, float* __restrict__ top_w, int* __restrict__ counts,
    unsigned short* __restrict__ xb,
    const float* __restrict__ W1f, const float* __restrict__ W3f,
    unsigned short* __restrict__ W1T, unsigned short* __restrict__ W3T)
{
    __shared__ unsigned short L[64][65];
    int bid = blockIdx.x;

    if (bid >= N_TOK / 4) {
        // tcvt role: 16384 blocks; W1 (z<8) / W3 (z>=8), [D][F] -> [F][D]
        int flat = bid - N_TOK / 4;
        int cx = flat & 63;                  // F/64
        int cy = (flat >> 6) & 15;           // D/64
        int z  = flat >> 10;                 // 0..15
        constexpr int R = DIM, C = FF;
        const float* s = ((z < NE) ? W1f : W3f) + (size_t)(z & 7) * R * C;
        unsigned short* d = ((z < NE) ? W1T : W3T) + (size_t)(z & 7) * R * C;
        tcvt_tile(s, d, R, C, cy * 64, cx * 64, L, threadIdx.x);
        return;
    }

    // router role: 4 tokens/block, 1 wave each
    int t = bid * 4 + (threadIdx.x >> 6);
    int lane = threadIdx.x & 63;
    float acc[NE];
#pragma unroll
    for (int e = 0; e < NE; ++e) acc[e] = 0.f;
    const float* xr = x + (size_t)t * DIM;
    unsigned short* xbr = xb + (size_t)t * DIM;
#pragma unroll
    for (int i = 0; i < DIM / 64; ++i) {
        int d = i * 64 + lane;
        float xv = xr[d];
        xbr[d] = f2bf(xv);
        const float4 w0 = *(const float4*)(Wg + (size_t)d * NE);
        const float4 w1 = *(const float4*)(Wg + (size_t)d * NE + 4);
        acc[0] += xv * w0.x; acc[1] += xv * w0.y; acc[2] += xv * w0.z; acc[3] += xv * w0.w;
        acc[4] += xv * w1.x; acc[5] += xv * w1.y; acc[6] += xv * w1.z; acc[7] += xv * w1.w;
    }
#pragma unroll
    for (int s = 32; s > 0; s >>= 1) {
#pragma unroll
        for (int e = 0; e < NE; ++e) acc[e] += __shfl_xor(acc[e], s);
    }
    if (lane == 0) {
        int i0 = 0; float v0 = acc[0];
#pragma unroll
        for (int e = 1; e < NE; ++e) if (acc[e] > v0) { v0 = acc[e]; i0 = e; }
        int i1 = -1; float v1 = -1e30f;
#pragma unroll
        for (int e = 0; e < NE; ++e) if (e != i0 && acc[e] > v1) { v1 = acc[e]; i1 = e; }
        float e1 = expf(v1 - v0);
        float inv = 1.f / (1.f + e1);
        top_i[t * 2 + 0] = i0;  top_i[t * 2 + 1] = i1;
        top_w[t * 2 + 0] = inv; top_w[t * 2 + 1] = e1 * inv;
        atomicAdd(&counts[i0], 1);
        atomicAdd(&counts[i1], 1);
    }
}

// ---------------- scan + tile descriptors ----------------
__global__ void scan_desc_kernel(const int* __restrict__ counts, int* __restrict__ seg)
{
    if (threadIdx.x != 0 || blockIdx.x != 0) return;
    int off = 0, nt = 0;
    for (int e = 0; e < NE; ++e) {
        seg[e] = off;
        int c = counts[e];
        int tiles = (c + TILE_R - 1) / TILE_R;
        for (int t = 0; t < tiles; ++t) {
            seg[16 + nt] = e;
            seg[96 + nt] = off + t * TILE_R;
            ++nt;
        }
        off += tiles * TILE_R;
    }
    seg[8] = nt;
}

// ---------------- build per-expert row lists; top_i becomes tok2row ----------------
__global__ __launch_bounds__(256) void build_kernel(
    int* __restrict__ top_i_rw,
    const int* __restrict__ seg, int* __restrict__ cursor,
    int* __restrict__ pair_tok)
{
    int idx = blockIdx.x * 256 + threadIdx.x;
    if (idx >= N_TOK * TOPK) return;
    int e = top_i_rw[idx];
    int pos = atomicAdd(&cursor[e], 1);
    int row = seg[e] + pos;
    pair_tok[row] = idx >> 1;
    top_i_rw[idx] = row;                  // tok2row (slot-private read-then-write)
}

// ---------------- fused: gemm1 (y%4==0, y/4<72) + W2 transpose-convert ----------------
// gemm1: proven single-buffer BK=64, 2 barriers/K-step, 128x128, 2x2 waves.
// tcvt role rows interleaved 3-per-gemm1-row (+40-row tail) so the BW-bound W2
// convert streams through free CU slots WHILE gemm1 computes (gemm2 launches
// after this kernel completes -> dependency safe).
__global__ __launch_bounds__(256, 2) void gemm1f_kernel(
    const unsigned short* __restrict__ xb, const unsigned short* __restrict__ W1T,
    const unsigned short* __restrict__ W3T,
    const int* __restrict__ pair_tok, const int* __restrict__ seg,
    unsigned short* __restrict__ h,
    const float* __restrict__ W2f, unsigned short* __restrict__ W2T)
{
    __shared__ __align__(16) char sm[49664];   // gemm1: As|B1s|B3s|toks ; tcvt: L[64][65]

    int yb = blockIdx.y;
    int q  = yb >> 2;
    bool isg = ((yb & 3) == 0) && (q < MAXT);

    if (!isg) {
        // tcvt role: 256 rows x 32 x-blocks = 8192 units; W2 [F][D] -> [D][F]
        int tr = (q < MAXT) ? (yb - q - 1) : (yb - MAXT);
        if (tr >= TCVT2_ROWS) return;        // guard (round-7 OOB bug)
        int flat = tr * 32 + blockIdx.x;
        int cx = flat & 15;                  // D/64
        int cy = (flat >> 4) & 63;           // F/64
        int e  = flat >> 10;                 // 0..7
        constexpr int R = FF, C = DIM;
        const float* s = W2f + (size_t)e * R * C;
        unsigned short* d = W2T + (size_t)e * R * C;
        tcvt_tile(s, d, R, C, cy * 64, cx * 64,
                  (unsigned short (*)[65])sm, threadIdx.x);
        return;
    }

    int tile = q;
    if (tile >= seg[8]) return;
    int e  = seg[16 + tile];
    int r0 = seg[96 + tile];
    int f0 = blockIdx.x * BN1;

    unsigned short* As  = (unsigned short*)sm;            // 16 KB
    unsigned short* B1s = (unsigned short*)(sm + 16384);  // 16 KB
    unsigned short* B3s = (unsigned short*)(sm + 32768);  // 16 KB
    int* toks = (int*)(sm + 49152);                       // 512 B

    int tid = threadIdx.x;
    if (tid < TILE_R) toks[tid] = pair_tok[r0 + tid];
    __syncthreads();

    int wid = tid >> 6, lane = tid & 63;
    int wm = wid >> 1, wn = wid & 1;             // 2x2 waves, each 64x64 per B
    int lrow = lane & 15;
    int lkb  = (lane >> 4) * 16;                 // frag k byte offset
    int axor = (lrow & 7) << 4;                  // read-side swizzle

    // pre-swizzled source col (elements) for glds staging:
    int sc = ((((lane & 7) * 16) ^ ((lane >> 3) << 4)) >> 1);

    const unsigned short* aSrc[4];
#pragma unroll
    for (int i = 0; i < 4; ++i) {
        int r = (wid * 4 + i) * 8 + (lane >> 3);
        int tok = toks[r]; if (tok < 0) tok = 0;   // pad rows: output discarded
        aSrc[i] = xb + (size_t)tok * DIM + sc;
    }
    const unsigned short *b1Src[4], *b3Src[4];
#pragma unroll
    for (int j = 0; j < 4; ++j) {
        int fl = (wid * 4 + j) * 8 + (lane >> 3);
        size_t rowoff = ((size_t)e * FF + f0 + fl) * DIM + sc;
        b1Src[j] = W1T + rowoff;
        b3Src[j] = W3T + rowoff;
    }

    f32x4 acc1[4][4], acc3[4][4];
    const f32x4 z4 = {0.f, 0.f, 0.f, 0.f};
#pragma unroll
    for (int m = 0; m < 4; ++m)
#pragma unroll
        for (int n = 0; n < 4; ++n) { acc1[m][n] = z4; acc3[m][n] = z4; }

    for (int k0 = 0; k0 < DIM; k0 += BK) {
#pragma unroll
        for (int i = 0; i < 4; ++i)
            GLDS16(aSrc[i] + k0, (char*)As + (wid * 4 + i) * 1024);
#pragma unroll
        for (int j = 0; j < 4; ++j) {
            GLDS16(b1Src[j] + k0, (char*)B1s + (wid * 4 + j) * 1024);
            GLDS16(b3Src[j] + k0, (char*)B3s + (wid * 4 + j) * 1024);
        }
        __syncthreads();   // drains vmcnt (glds) + barrier

#pragma unroll
        for (int kk = 0; kk < 2; ++kk) {
            int kb = kk * 64 + lkb;
            bf16x8 a[4], b1[4], b3[4];
#pragma unroll
            for (int m = 0; m < 4; ++m) {
                int row = wm * 64 + m * 16 + lrow;
                a[m] = *(const bf16x8*)((const char*)As + row * 128 + (kb ^ axor));
            }
#pragma unroll
            for (int n = 0; n < 4; ++n) {
                int row = wn * 64 + n * 16 + lrow;
                b1[n] = *(const bf16x8*)((const char*)B1s + row * 128 + (kb ^ axor));
                b3[n] = *(const bf16x8*)((const char*)B3s + row * 128 + (kb ^ axor));
            }
#pragma unroll
            for (int m = 0; m < 4; ++m)
#pragma unroll
                for (int n = 0; n < 4; ++n) {
                    acc1[m][n] = __builtin_amdgcn_mfma_f32_16x16x32_bf16(a[m], b1[n], acc1[m][n], 0, 0, 0);
                    acc3[m][n] = __builtin_amdgcn_mfma_f32_16x16x32_bf16(a[m], b3[n], acc3[m][n], 0, 0, 0);
                }
        }
        __syncthreads();
    }

    // epilogue: silu via v_rcp_f32 (1-ulp approx; absmax budget 6e-3)
    int lj = (lane >> 4) * 4;
#pragma unroll
    for (int m = 0; m < 4; ++m)
#pragma unroll
        for (int n = 0; n < 4; ++n)
#pragma unroll
            for (int j = 0; j < 4; ++j) {
                float h1 = acc1[m][n][j];
                float h3 = acc3[m][n][j];
                float s  = h1 * h3 * __builtin_amdgcn_rcpf(1.f + __expf(-h1));
                int row = r0 + wm * 64 + m * 16 + lj + j;
                int col = f0 + wn * 64 + n * 16 + lrow;
                h[(size_t)row * FF + col] = f2bf(s);
            }
}

// ---------------- gemm2: y(+y2) = h @ W2[e], DUAL-B 128x256, split-K=2 ----------------
// Two 128-col W2T tiles (d0, d0+128) share one A tile: per wave per K-step the
// loop runs 64 MFMA / 12 glds / 24 ds_reads -- gemm1's proven schedule/ratio.
// Single-buffer BK=64, 2 __syncthreads per K-step, 48KB LDS, 2 blocks/CU.
// Grid 576 = 2 khalf x (8 x8 x 4 dpair x 9 t9), XCD-chunked; ~528 real blocks
// = one full 512-slot batch + small remnant (was 1056 blocks / 2.06 batches).
__global__ __launch_bounds__(256, 2) void gemm2f_kernel(
    const unsigned short* __restrict__ h, const unsigned short* __restrict__ W2T,
    const int* __restrict__ seg, float* __restrict__ y, float* __restrict__ y2)
{
    int bid   = blockIdx.x;
    int khalf = bid / (MAXT * 4);
    int b2    = bid - khalf * (MAXT * 4);   // 0..287
    int x8    = b2 & 7;
    int dpair = (b2 >> 3) & 3;
    int t9    = b2 >> 5;                    // 0..8
    int tile  = x8 * (MAXT / 8) + t9;
    if (tile >= seg[8]) return;
    int e  = seg[16 + tile];
    int r0 = seg[96 + tile];
    int d0 = dpair * 256;
    int kbase = khalf * (FF / KSPL);

    __shared__ unsigned short As[TILE_R * BK];   // 16 KB
    __shared__ unsigned short Bas[128 * BK];     // 16 KB
    __shared__ unsigned short Bbs[128 * BK];     // 16 KB

    int tid = threadIdx.x;
    int wid = tid >> 6, lane = tid & 63;
    int wm = wid >> 1, wn = wid & 1;
    int lrow = lane & 15;
    int lkb  = (lane >> 4) * 16;
    int axor = (lrow & 7) << 4;
    int sc = ((((lane & 7) * 16) ^ ((lane >> 3) << 4)) >> 1);

    const unsigned short* aSrc[4];
#pragma unroll
    for (int i = 0; i < 4; ++i) {
        int r = (wid * 4 + i) * 8 + (lane >> 3);
        aSrc[i] = h + (size_t)(r0 + r) * FF + kbase + sc;
    }
    const unsigned short *baSrc[4], *bbSrc[4];
#pragma unroll
    for (int j = 0; j < 4; ++j) {
        int dl = (wid * 4 + j) * 8 + (lane >> 3);
        baSrc[j] = W2T + ((size_t)e * DIM + d0 + dl)       * FF + kbase + sc;
        bbSrc[j] = W2T + ((size_t)e * DIM + d0 + 128 + dl) * FF + kbase + sc;
    }

    f32x4 acca[4][4], accb[4][4];
    const f32x4 z4 = {0.f, 0.f, 0.f, 0.f};
#pragma unroll
    for (int m = 0; m < 4; ++m)
#pragma unroll
        for (int n = 0; n < 4; ++n) { acca[m][n] = z4; accb[m][n] = z4; }

    for (int k0 = 0; k0 < FF / KSPL; k0 += BK) {
#pragma unroll
        for (int i = 0; i < 4; ++i)
            GLDS16(aSrc[i] + k0, (char*)As + (wid * 4 + i) * 1024);
#pragma unroll
        for (int j = 0; j < 4; ++j) {
            GLDS16(baSrc[j] + k0, (char*)Bas + (wid * 4 + j) * 1024);
            GLDS16(bbSrc[j] + k0, (char*)Bbs + (wid * 4 + j) * 1024);
        }
        __syncthreads();   // drains vmcnt (glds) + barrier

#pragma unroll
        for (int kk = 0; kk < 2; ++kk) {
            int kb = kk * 64 + lkb;
            bf16x8 a[4], ba[4], bb[4];
#pragma unroll
            for (int m = 0; m < 4; ++m) {
                int row = wm * 64 + m * 16 + lrow;
                a[m] = *(const bf16x8*)((const char*)As + row * 128 + (kb ^ axor));
            }
#pragma unroll
            for (int n = 0; n < 4; ++n) {
                int row = wn * 64 + n * 16 + lrow;
                ba[n] = *(const bf16x8*)((const char*)Bas + row * 128 + (kb ^ axor));
                bb[n] = *(const bf16x8*)((const char*)Bbs + row * 128 + (kb ^ axor));
            }
#pragma unroll
            for (int m = 0; m < 4; ++m)
#pragma unroll
                for (int n = 0; n < 4; ++n) {
                    acca[m][n] = __builtin_amdgcn_mfma_f32_16x16x32_bf16(a[m], ba[n], acca[m][n], 0, 0, 0);
                    accb[m][n] = __builtin_amdgcn_mfma_f32_16x16x32_bf16(a[m], bb[n], accb[m][n], 0, 0, 0);
                }
        }
        __syncthreads();
    }

    // epilogue: direct scattered f32 stores (two 128-col halves)
    float* yt = khalf ? y2 : y;
    int lj = (lane >> 4) * 4;
#pragma unroll
    for (int m = 0; m < 4; ++m)
#pragma unroll
        for (int n = 0; n < 4; ++n)
#pragma unroll
            for (int j = 0; j < 4; ++j) {
                int row = r0 + wm * 64 + m * 16 + lj + j;     // pad rows: never combined
                int col = d0 + wn * 64 + n * 16 + lrow;
                yt[(size_t)row * DIM + col]       = acca[m][n][j];
                yt[(size_t)row * DIM + col + 128] = accb[m][n][j];
            }
}

// ---------------- combine: out[tok] = w0*(y[r0]+y2[r0]) + w1*(y[r1]+y2[r1]) ----------------
__global__ __launch_bounds__(256) void combine_kernel(
    const float* __restrict__ y, const float* __restrict__ y2,
    const int* __restrict__ tok2row,
    const float* __restrict__ top_w, float* __restrict__ out)
{
    int t = blockIdx.x;
    int c = threadIdx.x * 4;
    int r0 = tok2row[t * 2], r1 = tok2row[t * 2 + 1];
    float w0 = top_w[t * 2], w1 = top_w[t * 2 + 1];
    float4 a0 = *(const float4*)(y  + (size_t)r0 * DIM + c);
    float4 a1 = *(const float4*)(y2 + (size_t)r0 * DIM + c);
    float4 b0 = *(const float4*)(y  + (size_t)r1 * DIM + c);
    float4 b1 = *(const float4*)(y2 + (size_t)r1 * DIM + c);
    float4 o;
    o.x = w0 * (a0.x + a1.x) + w1 * (b0.x + b1.x);
    o.y = w0 * (a0.y + a1.y) + w1 * (b0.y + b1.y);
    o.z = w0 * (a0.z + a1.z) + w1 * (b0.z + b1.z);
    o.w = w0 * (a0.w + a1.w) + w1 * (b0.w + b1.w);
    *(float4*)(out + (size_t)t * DIM + c) = o;
}

extern "C" void kernel_launch(void* const* d_in, const int* in_sizes, int n_in,
                              void* d_out, int out_size, void* d_ws, size_t ws_size,
                              hipStream_t stream)
{
    const float* x  = (const float*)d_in[0];
    const float* Wg = (const float*)d_in[1];
    const float* W1 = (const float*)d_in[2];
    const float* W3 = (const float*)d_in[3];
    const float* W2 = (const float*)d_in[4];
    float* out = (float*)d_out;

    char* ws = (char*)d_ws;
    int*   top_i    = (int*)(ws + OFF_TOPI);   // becomes tok2row after build
    float* top_w    = (float*)(ws + OFF_TOPW);
    int*   counts   = (int*)(ws + OFF_CNT);
    int*   cursor   = (int*)(ws + OFF_CNT + 128);
    int*   seg      = (int*)(ws + OFF_SEG);
    int*   pair_tok = (int*)(ws + OFF_PTOK);
    unsigned short* xb  = (unsigned short*)(ws + OFF_XBF);
    unsigned short* h   = (unsigned short*)(ws + OFF_H);
    unsigned short* W1T = (unsigned short*)(ws + OFF_W1T);
    unsigned short* W3T = (unsigned short*)(ws + OFF_W3T);
    unsigned short* W2T = (unsigned short*)(ws + OFF_W2T);
    float* y  = (float*)(ws + OFF_Y);
    float* y2 = (float*)(ws + OFF_Y2);

    hipMemsetAsync(counts, 0, 512, stream);
    hipMemsetAsync(pair_tok, 0xFF, MAXROWS * sizeof(int), stream);

    // fused router + W1/W3 convert: 1024 router blocks + 16384 tcvt blocks
    router_tcvt13_kernel<<<N_TOK / 4 + 16384, 256, 0, stream>>>(
        x, Wg, top_i, top_w, counts, xb, W1, W3, W1T, W3T);
    scan_desc_kernel<<<1, 64, 0, stream>>>(counts, seg);
    build_kernel<<<(N_TOK * TOPK + 255) / 256, 256, 0, stream>>>(top_i, seg, cursor, pair_tok);

    // fused gemm1 + W2 convert: 72 gemm1 y-rows + 256 tcvt y-rows = 328
    dim3 g1(FF / BN1, G1_YDIM);
    gemm1f_kernel<<<g1, 256, 0, stream>>>(xb, W1T, W3T, pair_tok, seg, h, W2, W2T);
    gemm2f_kernel<<<MAXT * 4 * KSPL, 256, 0, stream>>>(h, W2T, seg, y, y2);
    combine_kernel<<<N_TOK, 256, 0, stream>>>(y, y2, top_i, top_w, out);
}

// Round 10
// 508.304 us; speedup vs baseline: 1.0222x; 1.0222x over previous
//
#include <hip/hip_runtime.h>
#include <hip/hip_bf16.h>

// MoE SwiGLU FFN, top-2 of 8 experts. B=2,T=2048 -> N=4096 tokens, D=1024, F=4096.
//
//   router+tcvt13 : fused dispatch. bid<1024: router (4 tok/block, fp32 logits,
//                   top-2, softmax, x->bf16). bid>=1024: W1/W3 [E][D][F]->[E][F][D].
//   scan/build    : per-expert 128-row padded compaction; pair_tok[row] = tok*2+slot
//   gemm1f+tcvtW2 : fused dispatch, grid y=328: y%4==0 && y/4<72 -> gemm1 tiles
//                   (proven 2-barrier 128x128 loop); other 256 rows -> W2 convert
//                   [E][F][D]->[E][D][F] overlapped under gemm1 compute.
//   gemm2f        : ROUND-8 loop verbatim (128x128, BK=64 dbuf, counted vmcnt(8),
//                   split-K=2, grid 1152). NEW epilogue: atomicAdd of
//                   top_w[idx]*acc directly into out (16MB, L2-resident RMW) --
//                   kills the 75MB y-stores, 150MB combine reads, and the combine
//                   launch. ROUND-9 LESSON: dual-B 128x256 single-buffer gemm2
//                   regressed +37us (lost dbuf cover + 528-on-512 tail); reverted.
//
// NOTE (rounds 1/2/4/5): deep-pipeline gemm1 variants all REGRESSED
// (237/318/224/270 us vs 185). Do not retry without changing read:MFMA ratio.

typedef float f32x4 __attribute__((ext_vector_type(4)));
typedef __bf16 bf16x8 __attribute__((ext_vector_type(8)));

constexpr int N_TOK = 4096;
constexpr int DIM   = 1024;
constexpr int FF    = 4096;
constexpr int NE    = 8;
constexpr int TOPK  = 2;
constexpr int TILE_R = 128;
constexpr int MAXROWS = 9216;             // 8192 + 8*128 padding capacity
constexpr int MAXT    = MAXROWS / TILE_R; // 72

constexpr int BK  = 64;
constexpr int BN1 = 128;                  // gemm1 F-tile
constexpr int BN2 = 128;                  // gemm2 D-tile
constexpr int KSPL = 2;                   // gemm2 split-K

constexpr int TCVT2_ROWS = 256;           // W2 tcvt units / 32 x-blocks
constexpr int G1_YDIM = MAXT * 4 + (TCVT2_ROWS - MAXT * 3);   // 288 + 40 = 328

// ---- workspace offsets ----
constexpr size_t OFF_TOPI   = 0;          // top_i (expert ids; consumed by build)
constexpr size_t OFF_TOPW   = 32768;
constexpr size_t OFF_CNT    = 65536;      // counts[8] @ +0, cursor[8] @ +128
constexpr size_t OFF_SEG    = 66048;
constexpr size_t OFF_PTOK   = 67072;
constexpr size_t OFF_XBF    = 140800;
constexpr size_t OFF_H      = OFF_XBF + (size_t)N_TOK * DIM * 2;
constexpr size_t OFF_W1T    = OFF_H   + (size_t)MAXROWS * FF * 2;
constexpr size_t OFF_W3T    = OFF_W1T + (size_t)NE * DIM * FF * 2;
constexpr size_t OFF_W2T    = OFF_W3T + (size_t)NE * DIM * FF * 2;

static __device__ __forceinline__ unsigned short f2bf(float f) {
    unsigned int x = __float_as_uint(f);
    x += 0x7FFFu + ((x >> 16) & 1u);    // round-to-nearest-even
    return (unsigned short)(x >> 16);
}

// async global->LDS, 16B per lane. LDS dest = wave-uniform base + lane*16 (linear);
// global src is per-lane (pre-swizzled for the XOR involution).
#define GLDS16(gsrc, ldst) \
    __builtin_amdgcn_global_load_lds( \
        (const __attribute__((address_space(1))) void*)(gsrc), \
        (__attribute__((address_space(3))) void*)(ldst), 16, 0, 0)

// raw barrier with compiler memory fences on both sides (no vmcnt drain)
static __device__ __forceinline__ void wg_barrier() {
    asm volatile("" ::: "memory");
    __builtin_amdgcn_s_barrier();
    asm volatile("" ::: "memory");
}

// shared 64x64 transpose-convert tile body (fp32 [R][C] tile -> bf16 [C][R])
static __device__ __forceinline__ void tcvt_tile(
    const float* __restrict__ s, unsigned short* __restrict__ d,
    int R, int C, int rt, int ct, unsigned short (*L)[65], int t)
{
    int r = t >> 4, c4 = (t & 15) * 4;
#pragma unroll
    for (int i = 0; i < 4; ++i) {
        float4 v = *(const float4*)(s + (size_t)(rt + r + i * 16) * C + ct + c4);
        L[r + i * 16][c4 + 0] = f2bf(v.x);
        L[r + i * 16][c4 + 1] = f2bf(v.y);
        L[r + i * 16][c4 + 2] = f2bf(v.z);
        L[r + i * 16][c4 + 3] = f2bf(v.w);
    }
    __syncthreads();
#pragma unroll
    for (int it = 0; it < 2; ++it) {
        int item = t + it * 256;
        int c  = item >> 3;
        int r8 = (item & 7) * 8;
        unsigned int w0 = (unsigned int)L[r8 + 0][c] | ((unsigned int)L[r8 + 1][c] << 16);
        unsigned int w1 = (unsigned int)L[r8 + 2][c] | ((unsigned int)L[r8 + 3][c] << 16);
        unsigned int w2 = (unsigned int)L[r8 + 4][c] | ((unsigned int)L[r8 + 5][c] << 16);
        unsigned int w3 = (unsigned int)L[r8 + 6][c] | ((unsigned int)L[r8 + 7][c] << 16);
        *(uint4*)(d + (size_t)(ct + c) * R + rt + r8) = make_uint4(w0, w1, w2, w3);
    }
}

// ---------------- fused: router (bid<1024) + W1/W3 transpose-convert ----------------
__global__ __launch_bounds__(256) void router_tcvt13_kernel(
    const float* __restrict__ x, const float* __restrict__ Wg,
    int* __restrict__ top_i, float* __restrict__ top_w, int* __restrict__ counts,
    unsigned short* __restrict__ xb,
    const float* __restrict__ W1f, const float* __restrict__ W3f,
    unsigned short* __restrict__ W1T, unsigned short* __restrict__ W3T)
{
    __shared__ unsigned short L[64][65];
    int bid = blockIdx.x;

    if (bid >= N_TOK / 4) {
        // tcvt role: 16384 blocks; W1 (z<8) / W3 (z>=8), [D][F] -> [F][D]
        int flat = bid - N_TOK / 4;
        int cx = flat & 63;                  // F/64
        int cy = (flat >> 6) & 15;           // D/64
        int z  = flat >> 10;                 // 0..15
        constexpr int R = DIM, C = FF;
        const float* s = ((z < NE) ? W1f : W3f) + (size_t)(z & 7) * R * C;
        unsigned short* d = ((z < NE) ? W1T : W3T) + (size_t)(z & 7) * R * C;
        tcvt_tile(s, d, R, C, cy * 64, cx * 64, L, threadIdx.x);
        return;
    }

    // router role: 4 tokens/block, 1 wave each
    int t = bid * 4 + (threadIdx.x >> 6);
    int lane = threadIdx.x & 63;
    float acc[NE];
#pragma unroll
    for (int e = 0; e < NE; ++e) acc[e] = 0.f;
    const float* xr = x + (size_t)t * DIM;
    unsigned short* xbr = xb + (size_t)t * DIM;
#pragma unroll
    for (int i = 0; i < DIM / 64; ++i) {
        int d = i * 64 + lane;
        float xv = xr[d];
        xbr[d] = f2bf(xv);
        const float4 w0 = *(const float4*)(Wg + (size_t)d * NE);
        const float4 w1 = *(const float4*)(Wg + (size_t)d * NE + 4);
        acc[0] += xv * w0.x; acc[1] += xv * w0.y; acc[2] += xv * w0.z; acc[3] += xv * w0.w;
        acc[4] += xv * w1.x; acc[5] += xv * w1.y; acc[6] += xv * w1.z; acc[7] += xv * w1.w;
    }
#pragma unroll
    for (int s = 32; s > 0; s >>= 1) {
#pragma unroll
        for (int e = 0; e < NE; ++e) acc[e] += __shfl_xor(acc[e], s);
    }
    if (lane == 0) {
        int i0 = 0; float v0 = acc[0];
#pragma unroll
        for (int e = 1; e < NE; ++e) if (acc[e] > v0) { v0 = acc[e]; i0 = e; }
        int i1 = -1; float v1 = -1e30f;
#pragma unroll
        for (int e = 0; e < NE; ++e) if (e != i0 && acc[e] > v1) { v1 = acc[e]; i1 = e; }
        float e1 = expf(v1 - v0);
        float inv = 1.f / (1.f + e1);
        top_i[t * 2 + 0] = i0;  top_i[t * 2 + 1] = i1;
        top_w[t * 2 + 0] = inv; top_w[t * 2 + 1] = e1 * inv;
        atomicAdd(&counts[i0], 1);
        atomicAdd(&counts[i1], 1);
    }
}

// ---------------- scan + tile descriptors ----------------
__global__ void scan_desc_kernel(const int* __restrict__ counts, int* __restrict__ seg)
{
    if (threadIdx.x != 0 || blockIdx.x != 0) return;
    int off = 0, nt = 0;
    for (int e = 0; e < NE; ++e) {
        seg[e] = off;
        int c = counts[e];
        int tiles = (c + TILE_R - 1) / TILE_R;
        for (int t = 0; t < tiles; ++t) {
            seg[16 + nt] = e;
            seg[96 + nt] = off + t * TILE_R;
            ++nt;
        }
        off += tiles * TILE_R;
    }
    seg[8] = nt;
}

// ---------------- build per-expert row lists; pair_tok[row] = idx (tok*2+slot) ----------------
__global__ __launch_bounds__(256) void build_kernel(
    const int* __restrict__ top_i,
    const int* __restrict__ seg, int* __restrict__ cursor,
    int* __restrict__ pair_tok)
{
    int idx = blockIdx.x * 256 + threadIdx.x;
    if (idx >= N_TOK * TOPK) return;
    int e = top_i[idx];
    int pos = atomicAdd(&cursor[e], 1);
    int row = seg[e] + pos;
    pair_tok[row] = idx;                  // tok = idx>>1, slot weight = top_w[idx]
}

// ---------------- fused: gemm1 (y%4==0, y/4<72) + W2 transpose-convert ----------------
// gemm1: proven single-buffer BK=64, 2 barriers/K-step, 128x128, 2x2 waves.
// tcvt role rows interleaved 3-per-gemm1-row (+40-row tail) so the BW-bound W2
// convert streams through free CU slots WHILE gemm1 computes (gemm2 launches
// after this kernel completes -> dependency safe).
__global__ __launch_bounds__(256, 2) void gemm1f_kernel(
    const unsigned short* __restrict__ xb, const unsigned short* __restrict__ W1T,
    const unsigned short* __restrict__ W3T,
    const int* __restrict__ pair_tok, const int* __restrict__ seg,
    unsigned short* __restrict__ h,
    const float* __restrict__ W2f, unsigned short* __restrict__ W2T)
{
    __shared__ __align__(16) char sm[49664];   // gemm1: As|B1s|B3s|toks ; tcvt: L[64][65]

    int yb = blockIdx.y;
    int q  = yb >> 2;
    bool isg = ((yb & 3) == 0) && (q < MAXT);

    if (!isg) {
        // tcvt role: 256 rows x 32 x-blocks = 8192 units; W2 [F][D] -> [D][F]
        int tr = (q < MAXT) ? (yb - q - 1) : (yb - MAXT);
        if (tr >= TCVT2_ROWS) return;        // guard (round-7 OOB bug)
        int flat = tr * 32 + blockIdx.x;
        int cx = flat & 15;                  // D/64
        int cy = (flat >> 4) & 63;           // F/64
        int e  = flat >> 10;                 // 0..7
        constexpr int R = FF, C = DIM;
        const float* s = W2f + (size_t)e * R * C;
        unsigned short* d = W2T + (size_t)e * R * C;
        tcvt_tile(s, d, R, C, cy * 64, cx * 64,
                  (unsigned short (*)[65])sm, threadIdx.x);
        return;
    }

    int tile = q;
    if (tile >= seg[8]) return;
    int e  = seg[16 + tile];
    int r0 = seg[96 + tile];
    int f0 = blockIdx.x * BN1;

    unsigned short* As  = (unsigned short*)sm;            // 16 KB
    unsigned short* B1s = (unsigned short*)(sm + 16384);  // 16 KB
    unsigned short* B3s = (unsigned short*)(sm + 32768);  // 16 KB
    int* toks = (int*)(sm + 49152);                       // 512 B

    int tid = threadIdx.x;
    if (tid < TILE_R) toks[tid] = pair_tok[r0 + tid];
    __syncthreads();

    int wid = tid >> 6, lane = tid & 63;
    int wm = wid >> 1, wn = wid & 1;             // 2x2 waves, each 64x64 per B
    int lrow = lane & 15;
    int lkb  = (lane >> 4) * 16;                 // frag k byte offset
    int axor = (lrow & 7) << 4;                  // read-side swizzle

    // pre-swizzled source col (elements) for glds staging:
    int sc = ((((lane & 7) * 16) ^ ((lane >> 3) << 4)) >> 1);

    const unsigned short* aSrc[4];
#pragma unroll
    for (int i = 0; i < 4; ++i) {
        int r = (wid * 4 + i) * 8 + (lane >> 3);
        int pt = toks[r];
        int tok = (pt < 0) ? 0 : (pt >> 1);        // pad rows: output discarded
        aSrc[i] = xb + (size_t)tok * DIM + sc;
    }
    const unsigned short *b1Src[4], *b3Src[4];
#pragma unroll
    for (int j = 0; j < 4; ++j) {
        int fl = (wid * 4 + j) * 8 + (lane >> 3);
        size_t rowoff = ((size_t)e * FF + f0 + fl) * DIM + sc;
        b1Src[j] = W1T + rowoff;
        b3Src[j] = W3T + rowoff;
    }

    f32x4 acc1[4][4], acc3[4][4];
    const f32x4 z4 = {0.f, 0.f, 0.f, 0.f};
#pragma unroll
    for (int m = 0; m < 4; ++m)
#pragma unroll
        for (int n = 0; n < 4; ++n) { acc1[m][n] = z4; acc3[m][n] = z4; }

    for (int k0 = 0; k0 < DIM; k0 += BK) {
#pragma unroll
        for (int i = 0; i < 4; ++i)
            GLDS16(aSrc[i] + k0, (char*)As + (wid * 4 + i) * 1024);
#pragma unroll
        for (int j = 0; j < 4; ++j) {
            GLDS16(b1Src[j] + k0, (char*)B1s + (wid * 4 + j) * 1024);
            GLDS16(b3Src[j] + k0, (char*)B3s + (wid * 4 + j) * 1024);
        }
        __syncthreads();   // drains vmcnt (glds) + barrier

#pragma unroll
        for (int kk = 0; kk < 2; ++kk) {
            int kb = kk * 64 + lkb;
            bf16x8 a[4], b1[4], b3[4];
#pragma unroll
            for (int m = 0; m < 4; ++m) {
                int row = wm * 64 + m * 16 + lrow;
                a[m] = *(const bf16x8*)((const char*)As + row * 128 + (kb ^ axor));
            }
#pragma unroll
            for (int n = 0; n < 4; ++n) {
                int row = wn * 64 + n * 16 + lrow;
                b1[n] = *(const bf16x8*)((const char*)B1s + row * 128 + (kb ^ axor));
                b3[n] = *(const bf16x8*)((const char*)B3s + row * 128 + (kb ^ axor));
            }
#pragma unroll
            for (int m = 0; m < 4; ++m)
#pragma unroll
                for (int n = 0; n < 4; ++n) {
                    acc1[m][n] = __builtin_amdgcn_mfma_f32_16x16x32_bf16(a[m], b1[n], acc1[m][n], 0, 0, 0);
                    acc3[m][n] = __builtin_amdgcn_mfma_f32_16x16x32_bf16(a[m], b3[n], acc3[m][n], 0, 0, 0);
                }
        }
        __syncthreads();
    }

    // epilogue: silu via v_rcp_f32 (1-ulp approx; absmax budget 6e-3)
    int lj = (lane >> 4) * 4;
#pragma unroll
    for (int m = 0; m < 4; ++m)
#pragma unroll
        for (int n = 0; n < 4; ++n)
#pragma unroll
            for (int j = 0; j < 4; ++j) {
                float h1 = acc1[m][n][j];
                float h3 = acc3[m][n][j];
                float s  = h1 * h3 * __builtin_amdgcn_rcpf(1.f + __expf(-h1));
                int row = r0 + wm * 64 + m * 16 + lj + j;
                int col = f0 + wn * 64 + n * 16 + lrow;
                h[(size_t)row * FF + col] = f2bf(s);
            }
}

// ---------------- gemm2: out += top_w * (h @ W2[e]), 128x128, split-K=2 ----------------
// Round-8 loop verbatim (dbuf, counted vmcnt(8), grid 1152, XCD-chunked).
// Fused-combine epilogue: atomicAdd(out[tok*DIM+col], top_w[idx]*acc) -- out is
// 16MB (L2-resident RMW); both khalves and both expert slots accumulate; pad
// rows (idx<0) skipped. out is zeroed by memset at launch start.
__global__ __launch_bounds__(256, 2) void gemm2f_kernel(
    const unsigned short* __restrict__ h, const unsigned short* __restrict__ W2T,
    const int* __restrict__ seg, const int* __restrict__ pair_tok,
    const float* __restrict__ top_w, float* __restrict__ out)
{
    int bid   = blockIdx.x;
    int khalf = bid / (MAXT * 8);
    int b2    = bid - khalf * (MAXT * 8);
    int x8   = b2 & 7;
    int dblk = (b2 >> 3) & 7;
    int t9   = (b2 >> 3) >> 3;
    int tile = x8 * (MAXT / 8) + t9;
    if (tile >= seg[8]) return;
    int e  = seg[16 + tile];
    int r0 = seg[96 + tile];
    int d0 = dblk * BN2;
    int kbase = khalf * (FF / KSPL);

    __shared__ __align__(16) char smem[2][32768];   // [buf][As 16KB | Bs 16KB]

    int tid = threadIdx.x;
    int wid = tid >> 6, lane = tid & 63;
    int wm = wid >> 1, wn = wid & 1;
    int lrow = lane & 15;
    int lkb  = (lane >> 4) * 16;
    int axor = (lrow & 7) << 4;
    int sc = ((((lane & 7) * 16) ^ ((lane >> 3) << 4)) >> 1);

    const unsigned short* aSrc[4];
#pragma unroll
    for (int i = 0; i < 4; ++i) {
        int r = (wid * 4 + i) * 8 + (lane >> 3);
        aSrc[i] = h + (size_t)(r0 + r) * FF + kbase + sc;
    }
    const unsigned short* bSrc[4];
#pragma unroll
    for (int j = 0; j < 4; ++j) {
        int dl = (wid * 4 + j) * 8 + (lane >> 3);
        bSrc[j] = W2T + ((size_t)e * DIM + d0 + dl) * FF + kbase + sc;
    }

#define STAGE2(buf, koff) { \
    char* AsB = smem[buf]; \
    char* BsB = smem[buf] + 16384; \
    _Pragma("unroll") \
    for (int i = 0; i < 4; ++i) \
        GLDS16(aSrc[i] + (koff), AsB + (wid * 4 + i) * 1024); \
    _Pragma("unroll") \
    for (int j = 0; j < 4; ++j) \
        GLDS16(bSrc[j] + (koff), BsB + (wid * 4 + j) * 1024); }

    f32x4 acc[4][4];
    const f32x4 z4 = {0.f, 0.f, 0.f, 0.f};
#pragma unroll
    for (int m = 0; m < 4; ++m)
#pragma unroll
        for (int n = 0; n < 4; ++n) acc[m][n] = z4;

    constexpr int NIT = (FF / KSPL) / BK;  // 32
    STAGE2(0, 0);
    int cur = 0;
    for (int it = 0; it < NIT; ++it) {
        if (it + 1 < NIT) {
            STAGE2(cur ^ 1, (it + 1) * BK);    // prefetch next K-step (8 loads)
            asm volatile("s_waitcnt vmcnt(8)" ::: "memory");  // cur staged; prefetch in flight
        } else {
            asm volatile("s_waitcnt vmcnt(0)" ::: "memory");
        }
        wg_barrier();                          // barrier 1: buf cur staged by ALL waves

        const char* AsR = smem[cur];
        const char* BsR = smem[cur] + 16384;
        bf16x8 a[2][4], b[2][4];
#pragma unroll
        for (int kk = 0; kk < 2; ++kk) {
            int kb = kk * 64 + lkb;
#pragma unroll
            for (int m = 0; m < 4; ++m) {
                int row = wm * 64 + m * 16 + lrow;
                a[kk][m] = *(const bf16x8*)(AsR + row * 128 + (kb ^ axor));
            }
#pragma unroll
            for (int n = 0; n < 4; ++n) {
                int row = wn * 64 + n * 16 + lrow;
                b[kk][n] = *(const bf16x8*)(BsR + row * 128 + (kb ^ axor));
            }
        }
        asm volatile("s_waitcnt lgkmcnt(0)" ::: "memory");
        wg_barrier();                          // barrier 2: reads retired; cur overwritable

#pragma unroll
        for (int kk = 0; kk < 2; ++kk)
#pragma unroll
            for (int m = 0; m < 4; ++m)
#pragma unroll
                for (int n = 0; n < 4; ++n)
                    acc[m][n] = __builtin_amdgcn_mfma_f32_16x16x32_bf16(a[kk][m], b[kk][n], acc[m][n], 0, 0, 0);
        cur ^= 1;
    }
#undef STAGE2

    // fused-combine epilogue: weighted atomic accumulate into out (L2-hot, 16MB)
    int lj = (lane >> 4) * 4;
#pragma unroll
    for (int m = 0; m < 4; ++m)
#pragma unroll
        for (int j = 0; j < 4; ++j) {
            int row = r0 + wm * 64 + m * 16 + lj + j;
            int pt = pair_tok[row];
            if (pt < 0) continue;                 // pad row
            float tw = top_w[pt];
            float* orow = out + (size_t)(pt >> 1) * DIM;
#pragma unroll
            for (int n = 0; n < 4; ++n) {
                int col = d0 + wn * 64 + n * 16 + lrow;
                atomicAdd(orow + col, tw * acc[m][n][j]);
            }
        }
}

extern "C" void kernel_launch(void* const* d_in, const int* in_sizes, int n_in,
                              void* d_out, int out_size, void* d_ws, size_t ws_size,
                              hipStream_t stream)
{
    const float* x  = (const float*)d_in[0];
    const float* Wg = (const float*)d_in[1];
    const float* W1 = (const float*)d_in[2];
    const float* W3 = (const float*)d_in[3];
    const float* W2 = (const float*)d_in[4];
    float* out = (float*)d_out;

    char* ws = (char*)d_ws;
    int*   top_i    = (int*)(ws + OFF_TOPI);
    float* top_w    = (float*)(ws + OFF_TOPW);
    int*   counts   = (int*)(ws + OFF_CNT);
    int*   cursor   = (int*)(ws + OFF_CNT + 128);
    int*   seg      = (int*)(ws + OFF_SEG);
    int*   pair_tok = (int*)(ws + OFF_PTOK);
    unsigned short* xb  = (unsigned short*)(ws + OFF_XBF);
    unsigned short* h   = (unsigned short*)(ws + OFF_H);
    unsigned short* W1T = (unsigned short*)(ws + OFF_W1T);
    unsigned short* W3T = (unsigned short*)(ws + OFF_W3T);
    unsigned short* W2T = (unsigned short*)(ws + OFF_W2T);

    hipMemsetAsync(counts, 0, 512, stream);
    hipMemsetAsync(pair_tok, 0xFF, MAXROWS * sizeof(int), stream);
    hipMemsetAsync(out, 0, (size_t)N_TOK * DIM * sizeof(float), stream);  // atomic-accum target

    // fused router + W1/W3 convert: 1024 router blocks + 16384 tcvt blocks
    router_tcvt13_kernel<<<N_TOK / 4 + 16384, 256, 0, stream>>>(
        x, Wg, top_i, top_w, counts, xb, W1, W3, W1T, W3T);
    scan_desc_kernel<<<1, 64, 0, stream>>>(counts, seg);
    build_kernel<<<(N_TOK * TOPK + 255) / 256, 256, 0, stream>>>(top_i, seg, cursor, pair_tok);

    // fused gemm1 + W2 convert: 72 gemm1 y-rows + 256 tcvt y-rows = 328
    dim3 g1(FF / BN1, G1_YDIM);
    gemm1f_kernel<<<g1, 256, 0, stream>>>(xb, W1T, W3T, pair_tok, seg, h, W2, W2T);
    gemm2f_kernel<<<MAXT * 8 * KSPL, 256, 0, stream>>>(h, W2T, seg, pair_tok, top_w, out);
}

// Round 11
// 480.835 us; speedup vs baseline: 1.0806x; 1.0571x over previous
//
#include <hip/hip_runtime.h>
#include <hip/hip_bf16.h>

// MoE SwiGLU FFN, top-2 of 8 experts. B=2,T=2048 -> N=4096 tokens, D=1024, F=4096.
//
//   router+tcvt13 : fused dispatch. bid<1024: router (4 tok/block, fp32 logits,
//                   top-2, softmax, x->bf16). bid>=1024: W1/W3 [E][D][F]->[E][F][D].
//   scan/build    : per-expert 128-row padded compaction; tok2row map
//   gemm1f+tcvtW2 : fused dispatch, grid y=328: y%4==0 && y/4<72 -> gemm1 tiles
//                   (proven 2-barrier 128x128 loop); other 256 rows -> W2 convert
//                   [E][F][D]->[E][D][F] overlapped under gemm1 compute.
//   gemm2f        : y = h @ W2[e]  [BK=64 dbuf, counted-vmcnt, split-K=2]
//   combine       : out[tok] = w0*(y[r0]+y2[r0]) + w1*(y[r1]+y2[r1])
//
// SETTLED BY MEASUREMENT (do not retry):
//  - gemm1 deep pipelines (BK=32 dbuf 237us, counted-vmcnt 2-phase 318us,
//    256-row 4-phase q-spread 224us / q0-burst 270us) ALL lose to the
//    2-barrier compiler-scheduled loop (185us; 207us with fused W2-tcvt).
//  - gemm2 dual-B 128x256 single-buffer: +37us (r9 — lost dbuf cover + tail).
//  - gemm2 atomic fused-combine epilogue: +25us (r10 — 18.9M scattered f32
//    atomics serialize the epilogue; y-stores + combine pass is cheaper).
//  This round-8 configuration (483us) is the verified floor of this
//  decomposition on MI355X.

typedef float f32x4 __attribute__((ext_vector_type(4)));
typedef __bf16 bf16x8 __attribute__((ext_vector_type(8)));

constexpr int N_TOK = 4096;
constexpr int DIM   = 1024;
constexpr int FF    = 4096;
constexpr int NE    = 8;
constexpr int TOPK  = 2;
constexpr int TILE_R = 128;
constexpr int MAXROWS = 9216;             // 8192 + 8*128 padding capacity
constexpr int MAXT    = MAXROWS / TILE_R; // 72

constexpr int BK  = 64;
constexpr int BN1 = 128;                  // gemm1 F-tile
constexpr int BN2 = 128;                  // gemm2 D-tile
constexpr int KSPL = 2;                   // gemm2 split-K

constexpr int TCVT2_ROWS = 256;           // W2 tcvt units / 32 x-blocks
constexpr int G1_YDIM = MAXT * 4 + (TCVT2_ROWS - MAXT * 3);   // 288 + 40 = 328

// ---- workspace offsets ----
constexpr size_t OFF_TOPI   = 0;          // top_i; rewritten by build -> tok2row
constexpr size_t OFF_TOPW   = 32768;
constexpr size_t OFF_CNT    = 65536;      // counts[8] @ +0, cursor[8] @ +128
constexpr size_t OFF_SEG    = 66048;
constexpr size_t OFF_PTOK   = 67072;
constexpr size_t OFF_XBF    = 140800;
constexpr size_t OFF_H      = OFF_XBF + (size_t)N_TOK * DIM * 2;
constexpr size_t OFF_W1T    = OFF_H   + (size_t)MAXROWS * FF * 2;
constexpr size_t OFF_W3T    = OFF_W1T + (size_t)NE * DIM * FF * 2;
constexpr size_t OFF_W2T    = OFF_W3T + (size_t)NE * DIM * FF * 2;
constexpr size_t OFF_Y      = OFF_W1T;    // y  [MAXROWS][DIM] f32 overlays W1T (dead after gemm1)
constexpr size_t OFF_Y2     = OFF_W3T;    // y2 [MAXROWS][DIM] f32 overlays W3T (dead after gemm1)

static __device__ __forceinline__ unsigned short f2bf(float f) {
    unsigned int x = __float_as_uint(f);
    x += 0x7FFFu + ((x >> 16) & 1u);    // round-to-nearest-even
    return (unsigned short)(x >> 16);
}

// async global->LDS, 16B per lane. LDS dest = wave-uniform base + lane*16 (linear);
// global src is per-lane (pre-swizzled for the XOR involution).
#define GLDS16(gsrc, ldst) \
    __builtin_amdgcn_global_load_lds( \
        (const __attribute__((address_space(1))) void*)(gsrc), \
        (__attribute__((address_space(3))) void*)(ldst), 16, 0, 0)

// raw barrier with compiler memory fences on both sides (no vmcnt drain)
static __device__ __forceinline__ void wg_barrier() {
    asm volatile("" ::: "memory");
    __builtin_amdgcn_s_barrier();
    asm volatile("" ::: "memory");
}

// shared 64x64 transpose-convert tile body (fp32 [R][C] tile -> bf16 [C][R])
static __device__ __forceinline__ void tcvt_tile(
    const float* __restrict__ s, unsigned short* __restrict__ d,
    int R, int C, int rt, int ct, unsigned short (*L)[65], int t)
{
    int r = t >> 4, c4 = (t & 15) * 4;
#pragma unroll
    for (int i = 0; i < 4; ++i) {
        float4 v = *(const float4*)(s + (size_t)(rt + r + i * 16) * C + ct + c4);
        L[r + i * 16][c4 + 0] = f2bf(v.x);
        L[r + i * 16][c4 + 1] = f2bf(v.y);
        L[r + i * 16][c4 + 2] = f2bf(v.z);
        L[r + i * 16][c4 + 3] = f2bf(v.w);
    }
    __syncthreads();
#pragma unroll
    for (int it = 0; it < 2; ++it) {
        int item = t + it * 256;
        int c  = item >> 3;
        int r8 = (item & 7) * 8;
        unsigned int w0 = (unsigned int)L[r8 + 0][c] | ((unsigned int)L[r8 + 1][c] << 16);
        unsigned int w1 = (unsigned int)L[r8 + 2][c] | ((unsigned int)L[r8 + 3][c] << 16);
        unsigned int w2 = (unsigned int)L[r8 + 4][c] | ((unsigned int)L[r8 + 5][c] << 16);
        unsigned int w3 = (unsigned int)L[r8 + 6][c] | ((unsigned int)L[r8 + 7][c] << 16);
        *(uint4*)(d + (size_t)(ct + c) * R + rt + r8) = make_uint4(w0, w1, w2, w3);
    }
}

// ---------------- fused: router (bid<1024) + W1/W3 transpose-convert ----------------
__global__ __launch_bounds__(256) void router_tcvt13_kernel(
    const float* __restrict__ x, const float* __restrict__ Wg,
    int* __restrict__ top_i, float* __restrict__ top_w, int* __restrict__ counts,
    unsigned short* __restrict__ xb,
    const float* __restrict__ W1f, const float* __restrict__ W3f,
    unsigned short* __restrict__ W1T, unsigned short* __restrict__ W3T)
{
    __shared__ unsigned short L[64][65];
    int bid = blockIdx.x;

    if (bid >= N_TOK / 4) {
        // tcvt role: 16384 blocks; W1 (z<8) / W3 (z>=8), [D][F] -> [F][D]
        int flat = bid - N_TOK / 4;
        int cx = flat & 63;                  // F/64
        int cy = (flat >> 6) & 15;           // D/64
        int z  = flat >> 10;                 // 0..15
        constexpr int R = DIM, C = FF;
        const float* s = ((z < NE) ? W1f : W3f) + (size_t)(z & 7) * R * C;
        unsigned short* d = ((z < NE) ? W1T : W3T) + (size_t)(z & 7) * R * C;
        tcvt_tile(s, d, R, C, cy * 64, cx * 64, L, threadIdx.x);
        return;
    }

    // router role: 4 tokens/block, 1 wave each
    int t = bid * 4 + (threadIdx.x >> 6);
    int lane = threadIdx.x & 63;
    float acc[NE];
#pragma unroll
    for (int e = 0; e < NE; ++e) acc[e] = 0.f;
    const float* xr = x + (size_t)t * DIM;
    unsigned short* xbr = xb + (size_t)t * DIM;
#pragma unroll
    for (int i = 0; i < DIM / 64; ++i) {
        int d = i * 64 + lane;
        float xv = xr[d];
        xbr[d] = f2bf(xv);
        const float4 w0 = *(const float4*)(Wg + (size_t)d * NE);
        const float4 w1 = *(const float4*)(Wg + (size_t)d * NE + 4);
        acc[0] += xv * w0.x; acc[1] += xv * w0.y; acc[2] += xv * w0.z; acc[3] += xv * w0.w;
        acc[4] += xv * w1.x; acc[5] += xv * w1.y; acc[6] += xv * w1.z; acc[7] += xv * w1.w;
    }
#pragma unroll
    for (int s = 32; s > 0; s >>= 1) {
#pragma unroll
        for (int e = 0; e < NE; ++e) acc[e] += __shfl_xor(acc[e], s);
    }
    if (lane == 0) {
        int i0 = 0; float v0 = acc[0];
#pragma unroll
        for (int e = 1; e < NE; ++e) if (acc[e] > v0) { v0 = acc[e]; i0 = e; }
        int i1 = -1; float v1 = -1e30f;
#pragma unroll
        for (int e = 0; e < NE; ++e) if (e != i0 && acc[e] > v1) { v1 = acc[e]; i1 = e; }
        float e1 = expf(v1 - v0);
        float inv = 1.f / (1.f + e1);
        top_i[t * 2 + 0] = i0;  top_i[t * 2 + 1] = i1;
        top_w[t * 2 + 0] = inv; top_w[t * 2 + 1] = e1 * inv;
        atomicAdd(&counts[i0], 1);
        atomicAdd(&counts[i1], 1);
    }
}

// ---------------- scan + tile descriptors ----------------
__global__ void scan_desc_kernel(const int* __restrict__ counts, int* __restrict__ seg)
{
    if (threadIdx.x != 0 || blockIdx.x != 0) return;
    int off = 0, nt = 0;
    for (int e = 0; e < NE; ++e) {
        seg[e] = off;
        int c = counts[e];
        int tiles = (c + TILE_R - 1) / TILE_R;
        for (int t = 0; t < tiles; ++t) {
            seg[16 + nt] = e;
            seg[96 + nt] = off + t * TILE_R;
            ++nt;
        }
        off += tiles * TILE_R;
    }
    seg[8] = nt;
}

// ---------------- build per-expert row lists; top_i becomes tok2row ----------------
__global__ __launch_bounds__(256) void build_kernel(
    int* __restrict__ top_i_rw,
    const int* __restrict__ seg, int* __restrict__ cursor,
    int* __restrict__ pair_tok)
{
    int idx = blockIdx.x * 256 + threadIdx.x;
    if (idx >= N_TOK * TOPK) return;
    int e = top_i_rw[idx];
    int pos = atomicAdd(&cursor[e], 1);
    int row = seg[e] + pos;
    pair_tok[row] = idx >> 1;
    top_i_rw[idx] = row;                  // tok2row (slot-private read-then-write)
}

// ---------------- fused: gemm1 (y%4==0, y/4<72) + W2 transpose-convert ----------------
// gemm1: proven single-buffer BK=64, 2 barriers/K-step, 128x128, 2x2 waves.
// tcvt role rows interleaved 3-per-gemm1-row (+40-row tail) so the BW-bound W2
// convert streams through free CU slots WHILE gemm1 computes (gemm2 launches
// after this kernel completes -> dependency safe).
__global__ __launch_bounds__(256, 2) void gemm1f_kernel(
    const unsigned short* __restrict__ xb, const unsigned short* __restrict__ W1T,
    const unsigned short* __restrict__ W3T,
    const int* __restrict__ pair_tok, const int* __restrict__ seg,
    unsigned short* __restrict__ h,
    const float* __restrict__ W2f, unsigned short* __restrict__ W2T)
{
    __shared__ __align__(16) char sm[49664];   // gemm1: As|B1s|B3s|toks ; tcvt: L[64][65]

    int yb = blockIdx.y;
    int q  = yb >> 2;
    bool isg = ((yb & 3) == 0) && (q < MAXT);

    if (!isg) {
        // tcvt role: 256 rows x 32 x-blocks = 8192 units; W2 [F][D] -> [D][F]
        int tr = (q < MAXT) ? (yb - q - 1) : (yb - MAXT);
        if (tr >= TCVT2_ROWS) return;        // guard (round-7 OOB bug)
        int flat = tr * 32 + blockIdx.x;
        int cx = flat & 15;                  // D/64
        int cy = (flat >> 4) & 63;           // F/64
        int e  = flat >> 10;                 // 0..7
        constexpr int R = FF, C = DIM;
        const float* s = W2f + (size_t)e * R * C;
        unsigned short* d = W2T + (size_t)e * R * C;
        tcvt_tile(s, d, R, C, cy * 64, cx * 64,
                  (unsigned short (*)[65])sm, threadIdx.x);
        return;
    }

    int tile = q;
    if (tile >= seg[8]) return;
    int e  = seg[16 + tile];
    int r0 = seg[96 + tile];
    int f0 = blockIdx.x * BN1;

    unsigned short* As  = (unsigned short*)sm;            // 16 KB
    unsigned short* B1s = (unsigned short*)(sm + 16384);  // 16 KB
    unsigned short* B3s = (unsigned short*)(sm + 32768);  // 16 KB
    int* toks = (int*)(sm + 49152);                       // 512 B

    int tid = threadIdx.x;
    if (tid < TILE_R) toks[tid] = pair_tok[r0 + tid];
    __syncthreads();

    int wid = tid >> 6, lane = tid & 63;
    int wm = wid >> 1, wn = wid & 1;             // 2x2 waves, each 64x64 per B
    int lrow = lane & 15;
    int lkb  = (lane >> 4) * 16;                 // frag k byte offset
    int axor = (lrow & 7) << 4;                  // read-side swizzle

    // pre-swizzled source col (elements) for glds staging:
    int sc = ((((lane & 7) * 16) ^ ((lane >> 3) << 4)) >> 1);

    const unsigned short* aSrc[4];
#pragma unroll
    for (int i = 0; i < 4; ++i) {
        int r = (wid * 4 + i) * 8 + (lane >> 3);
        int tok = toks[r]; if (tok < 0) tok = 0;   // pad rows: output discarded
        aSrc[i] = xb + (size_t)tok * DIM + sc;
    }
    const unsigned short *b1Src[4], *b3Src[4];
#pragma unroll
    for (int j = 0; j < 4; ++j) {
        int fl = (wid * 4 + j) * 8 + (lane >> 3);
        size_t rowoff = ((size_t)e * FF + f0 + fl) * DIM + sc;
        b1Src[j] = W1T + rowoff;
        b3Src[j] = W3T + rowoff;
    }

    f32x4 acc1[4][4], acc3[4][4];
    const f32x4 z4 = {0.f, 0.f, 0.f, 0.f};
#pragma unroll
    for (int m = 0; m < 4; ++m)
#pragma unroll
        for (int n = 0; n < 4; ++n) { acc1[m][n] = z4; acc3[m][n] = z4; }

    for (int k0 = 0; k0 < DIM; k0 += BK) {
#pragma unroll
        for (int i = 0; i < 4; ++i)
            GLDS16(aSrc[i] + k0, (char*)As + (wid * 4 + i) * 1024);
#pragma unroll
        for (int j = 0; j < 4; ++j) {
            GLDS16(b1Src[j] + k0, (char*)B1s + (wid * 4 + j) * 1024);
            GLDS16(b3Src[j] + k0, (char*)B3s + (wid * 4 + j) * 1024);
        }
        __syncthreads();   // drains vmcnt (glds) + barrier

#pragma unroll
        for (int kk = 0; kk < 2; ++kk) {
            int kb = kk * 64 + lkb;
            bf16x8 a[4], b1[4], b3[4];
#pragma unroll
            for (int m = 0; m < 4; ++m) {
                int row = wm * 64 + m * 16 + lrow;
                a[m] = *(const bf16x8*)((const char*)As + row * 128 + (kb ^ axor));
            }
#pragma unroll
            for (int n = 0; n < 4; ++n) {
                int row = wn * 64 + n * 16 + lrow;
                b1[n] = *(const bf16x8*)((const char*)B1s + row * 128 + (kb ^ axor));
                b3[n] = *(const bf16x8*)((const char*)B3s + row * 128 + (kb ^ axor));
            }
#pragma unroll
            for (int m = 0; m < 4; ++m)
#pragma unroll
                for (int n = 0; n < 4; ++n) {
                    acc1[m][n] = __builtin_amdgcn_mfma_f32_16x16x32_bf16(a[m], b1[n], acc1[m][n], 0, 0, 0);
                    acc3[m][n] = __builtin_amdgcn_mfma_f32_16x16x32_bf16(a[m], b3[n], acc3[m][n], 0, 0, 0);
                }
        }
        __syncthreads();
    }

    // epilogue: silu via v_rcp_f32 (1-ulp approx; absmax budget 6e-3)
    int lj = (lane >> 4) * 4;
#pragma unroll
    for (int m = 0; m < 4; ++m)
#pragma unroll
        for (int n = 0; n < 4; ++n)
#pragma unroll
            for (int j = 0; j < 4; ++j) {
                float h1 = acc1[m][n][j];
                float h3 = acc3[m][n][j];
                float s  = h1 * h3 * __builtin_amdgcn_rcpf(1.f + __expf(-h1));
                int row = r0 + wm * 64 + m * 16 + lj + j;
                int col = f0 + wn * 64 + n * 16 + lrow;
                h[(size_t)row * FF + col] = f2bf(s);
            }
}

// ---------------- gemm2: y(+y2) = h @ W2[e], 128x128, split-K=2, counted-vmcnt dbuf ----------------
// Grid 1152 = 2 khalf x (72 tiles x 8 dblk), XCD-chunked within each khalf.
// Each half reduces K/2=2048 and writes its own f32 partial (y / y2); combine sums.
__global__ __launch_bounds__(256, 2) void gemm2f_kernel(
    const unsigned short* __restrict__ h, const unsigned short* __restrict__ W2T,
    const int* __restrict__ seg, float* __restrict__ y, float* __restrict__ y2)
{
    int bid   = blockIdx.x;
    int khalf = bid / (MAXT * 8);
    int b2    = bid - khalf * (MAXT * 8);
    int x8   = b2 & 7;
    int dblk = (b2 >> 3) & 7;
    int t9   = (b2 >> 3) >> 3;
    int tile = x8 * (MAXT / 8) + t9;
    if (tile >= seg[8]) return;
    int e  = seg[16 + tile];
    int r0 = seg[96 + tile];
    int d0 = dblk * BN2;
    int kbase = khalf * (FF / KSPL);

    __shared__ __align__(16) char smem[2][32768];   // [buf][As 16KB | Bs 16KB]

    int tid = threadIdx.x;
    int wid = tid >> 6, lane = tid & 63;
    int wm = wid >> 1, wn = wid & 1;
    int lrow = lane & 15;
    int lkb  = (lane >> 4) * 16;
    int axor = (lrow & 7) << 4;
    int sc = ((((lane & 7) * 16) ^ ((lane >> 3) << 4)) >> 1);

    const unsigned short* aSrc[4];
#pragma unroll
    for (int i = 0; i < 4; ++i) {
        int r = (wid * 4 + i) * 8 + (lane >> 3);
        aSrc[i] = h + (size_t)(r0 + r) * FF + kbase + sc;
    }
    const unsigned short* bSrc[4];
#pragma unroll
    for (int j = 0; j < 4; ++j) {
        int dl = (wid * 4 + j) * 8 + (lane >> 3);
        bSrc[j] = W2T + ((size_t)e * DIM + d0 + dl) * FF + kbase + sc;
    }

#define STAGE2(buf, koff) { \
    char* AsB = smem[buf]; \
    char* BsB = smem[buf] + 16384; \
    _Pragma("unroll") \
    for (int i = 0; i < 4; ++i) \
        GLDS16(aSrc[i] + (koff), AsB + (wid * 4 + i) * 1024); \
    _Pragma("unroll") \
    for (int j = 0; j < 4; ++j) \
        GLDS16(bSrc[j] + (koff), BsB + (wid * 4 + j) * 1024); }

    f32x4 acc[4][4];
    const f32x4 z4 = {0.f, 0.f, 0.f, 0.f};
#pragma unroll
    for (int m = 0; m < 4; ++m)
#pragma unroll
        for (int n = 0; n < 4; ++n) acc[m][n] = z4;

    constexpr int NIT = (FF / KSPL) / BK;  // 32
    STAGE2(0, 0);
    int cur = 0;
    for (int it = 0; it < NIT; ++it) {
        if (it + 1 < NIT) {
            STAGE2(cur ^ 1, (it + 1) * BK);    // prefetch next K-step (8 loads)
            asm volatile("s_waitcnt vmcnt(8)" ::: "memory");  // cur staged; prefetch in flight
        } else {
            asm volatile("s_waitcnt vmcnt(0)" ::: "memory");
        }
        wg_barrier();                          // barrier 1: buf cur staged by ALL waves

        const char* AsR = smem[cur];
        const char* BsR = smem[cur] + 16384;
        bf16x8 a[2][4], b[2][4];
#pragma unroll
        for (int kk = 0; kk < 2; ++kk) {
            int kb = kk * 64 + lkb;
#pragma unroll
            for (int m = 0; m < 4; ++m) {
                int row = wm * 64 + m * 16 + lrow;
                a[kk][m] = *(const bf16x8*)(AsR + row * 128 + (kb ^ axor));
            }
#pragma unroll
            for (int n = 0; n < 4; ++n) {
                int row = wn * 64 + n * 16 + lrow;
                b[kk][n] = *(const bf16x8*)(BsR + row * 128 + (kb ^ axor));
            }
        }
        asm volatile("s_waitcnt lgkmcnt(0)" ::: "memory");
        wg_barrier();                          // barrier 2: reads retired; cur overwritable

#pragma unroll
        for (int kk = 0; kk < 2; ++kk)
#pragma unroll
            for (int m = 0; m < 4; ++m)
#pragma unroll
                for (int n = 0; n < 4; ++n)
                    acc[m][n] = __builtin_amdgcn_mfma_f32_16x16x32_bf16(a[kk][m], b[kk][n], acc[m][n], 0, 0, 0);
        cur ^= 1;
    }
#undef STAGE2

    // epilogue: direct scattered f32 stores (64B per 16-lane group)
    float* yt = khalf ? y2 : y;
    int lj = (lane >> 4) * 4;
#pragma unroll
    for (int m = 0; m < 4; ++m)
#pragma unroll
        for (int n = 0; n < 4; ++n)
#pragma unroll
            for (int j = 0; j < 4; ++j) {
                int row = r0 + wm * 64 + m * 16 + lj + j;     // pad rows: never combined
                int col = d0 + wn * 64 + n * 16 + lrow;
                yt[(size_t)row * DIM + col] = acc[m][n][j];
            }
}

// ---------------- combine: out[tok] = w0*(y[r0]+y2[r0]) + w1*(y[r1]+y2[r1]) ----------------
__global__ __launch_bounds__(256) void combine_kernel(
    const float* __restrict__ y, const float* __restrict__ y2,
    const int* __restrict__ tok2row,
    const float* __restrict__ top_w, float* __restrict__ out)
{
    int t = blockIdx.x;
    int c = threadIdx.x * 4;
    int r0 = tok2row[t * 2], r1 = tok2row[t * 2 + 1];
    float w0 = top_w[t * 2], w1 = top_w[t * 2 + 1];
    float4 a0 = *(const float4*)(y  + (size_t)r0 * DIM + c);
    float4 a1 = *(const float4*)(y2 + (size_t)r0 * DIM + c);
    float4 b0 = *(const float4*)(y  + (size_t)r1 * DIM + c);
    float4 b1 = *(const float4*)(y2 + (size_t)r1 * DIM + c);
    float4 o;
    o.x = w0 * (a0.x + a1.x) + w1 * (b0.x + b1.x);
    o.y = w0 * (a0.y + a1.y) + w1 * (b0.y + b1.y);
    o.z = w0 * (a0.z + a1.z) + w1 * (b0.z + b1.z);
    o.w = w0 * (a0.w + a1.w) + w1 * (b0.w + b1.w);
    *(float4*)(out + (size_t)t * DIM + c) = o;
}

extern "C" void kernel_launch(void* const* d_in, const int* in_sizes, int n_in,
                              void* d_out, int out_size, void* d_ws, size_t ws_size,
                              hipStream_t stream)
{
    const float* x  = (const float*)d_in[0];
    const float* Wg = (const float*)d_in[1];
    const float* W1 = (const float*)d_in[2];
    const float* W3 = (const float*)d_in[3];
    const float* W2 = (const float*)d_in[4];
    float* out = (float*)d_out;

    char* ws = (char*)d_ws;
    int*   top_i    = (int*)(ws + OFF_TOPI);   // becomes tok2row after build
    float* top_w    = (float*)(ws + OFF_TOPW);
    int*   counts   = (int*)(ws + OFF_CNT);
    int*   cursor   = (int*)(ws + OFF_CNT + 128);
    int*   seg      = (int*)(ws + OFF_SEG);
    int*   pair_tok = (int*)(ws + OFF_PTOK);
    unsigned short* xb  = (unsigned short*)(ws + OFF_XBF);
    unsigned short* h   = (unsigned short*)(ws + OFF_H);
    unsigned short* W1T = (unsigned short*)(ws + OFF_W1T);
    unsigned short* W3T = (unsigned short*)(ws + OFF_W3T);
    unsigned short* W2T = (unsigned short*)(ws + OFF_W2T);
    float* y  = (float*)(ws + OFF_Y);
    float* y2 = (float*)(ws + OFF_Y2);

    hipMemsetAsync(counts, 0, 512, stream);
    hipMemsetAsync(pair_tok, 0xFF, MAXROWS * sizeof(int), stream);

    // fused router + W1/W3 convert: 1024 router blocks + 16384 tcvt blocks
    router_tcvt13_kernel<<<N_TOK / 4 + 16384, 256, 0, stream>>>(
        x, Wg, top_i, top_w, counts, xb, W1, W3, W1T, W3T);
    scan_desc_kernel<<<1, 64, 0, stream>>>(counts, seg);
    build_kernel<<<(N_TOK * TOPK + 255) / 256, 256, 0, stream>>>(top_i, seg, cursor, pair_tok);

    // fused gemm1 + W2 convert: 72 gemm1 y-rows + 256 tcvt y-rows = 328
    dim3 g1(FF / BN1, G1_YDIM);
    gemm1f_kernel<<<g1, 256, 0, stream>>>(xb, W1T, W3T, pair_tok, seg, h, W2, W2T);
    gemm2f_kernel<<<MAXT * 8 * KSPL, 256, 0, stream>>>(h, W2T, seg, y, y2);
    combine_kernel<<<N_TOK, 256, 0, stream>>>(y, y2, top_i, top_w, out);
}